// Round 1
// 227.149 us; speedup vs baseline: 1.0079x; 1.0079x over previous
//
#include <hip/hip_runtime.h>

typedef _Float16 f16x8 __attribute__((ext_vector_type(8)));
typedef _Float16 f16x4 __attribute__((ext_vector_type(4)));
typedef float    f32x4 __attribute__((ext_vector_type(4)));

static constexpr float kLOW  = 0.02f;
static constexpr float kHIGH = 0.98f;

__device__ __forceinline__ float fast_sigmoid(float v) {
    return 1.0f / (1.0f + __expf(-v));
}
__device__ __forceinline__ float fast_rcp(float v) {
    return __builtin_amdgcn_rcpf(v);  // v_rcp_f32, ~1e-7 rel err
}

// R5: VALU was the bottleneck (VALUBusy 82%, MfmaUtil 4.8%). Layer 1
// (6->64, 384 scalar FMAs/row = ~40% of VALU work) moves onto the idle
// MFMA pipe. All three MFMA layers run "swapped" (C = W^T * h^T):
//   - A = W^T fragments are wave-invariant (lane n16 = out-feature,
//     k = q*8+j) -- identical index expressions to the old B-fragments.
//   - B = h^T fragments read contiguous [batch][k] rows (lane n16 =
//     batch col), so staging stays vectorized ds_read_b128.
//   - C layout (row q*4+r = 4 CONSECUTIVE features, col n16 = batch)
//     stores as one ds_write_b64/b128 per tile instead of scalar stores.
// Per-wave LDS slice 9216 B (unchanged, 4 blocks/CU):
//   h1 f16 [b][64+8pad] stride 144 @ 0..9216
//   h2 f16 [b][32+8pad] stride  80 @ 0..5120   (aliases h1; frags pre-read)
//   h3 f32 [b][16+4pad] stride  80 @ 0..5120   (aliases h2; frags pre-read)
//   x^T f16 [b][8] 16 B rows @ 8176..9200, zero tile @ 9200..9216
//     (h1 epilogue clobbers x region only AFTER x-fragments are read)
// Sinkhorn: gauge-fixed iterations (v2 == 1) for iters 1..9 drop one
// rcp each (A = diag(u)K diag(v) is invariant to v-rescaling between
// iterations); iteration 10 is the standard column step so final A ==
// reference exactly.
__global__ __launch_bounds__(256, 4) void sinkhorn_mlp_mfma(
    const float* __restrict__ margins,
    const float* __restrict__ W1, const float* __restrict__ b1,
    const float* __restrict__ W2, const float* __restrict__ b2,
    const float* __restrict__ W3, const float* __restrict__ b3,
    const float* __restrict__ W4, const float* __restrict__ b4,
    float* __restrict__ out_mus, float* __restrict__ out_V, int B)
{
    __shared__ __align__(16) char smem_all[4 * 9216];
    const int lane = threadIdx.x & 63;
    const int wid  = threadIdx.x >> 6;
    char* smem = smem_all + wid * 9216;

    const int n16 = lane & 15;   // MFMA tile row/col index
    const int q   = lane >> 4;   // quad 0..3

    const int row  = blockIdx.x * 256 + wid * 64 + lane;
    const int rowC = row < B ? row : (B - 1);

    // ---- load input row (f32 originals kept for sinkhorn margins) ----
    float x[6];
    {
        const float* mp = margins + (size_t)rowC * 6;
#pragma unroll
        for (int i = 0; i < 6; ++i) x[i] = mp[i];
    }

    // ---- stage x^T rows as f16 (k=0..5 data, 6..7 zero) + zero tile ----
    {
        f16x8 xr;
#pragma unroll
        for (int j = 0; j < 8; ++j) xr[j] = (_Float16)0.0f;
#pragma unroll
        for (int i = 0; i < 6; ++i) xr[i] = (_Float16)x[i];
        *(f16x8*)(smem + 8176 + lane * 16) = xr;
        if (lane == 0) {
            f16x8 z;
#pragma unroll
            for (int j = 0; j < 8; ++j) z[j] = (_Float16)0.0f;
            *(f16x8*)(smem + 9200) = z;   // shared zero tile for q>=1 reads
        }
    }

    // ---- wave-invariant A fragments (W^T), lane (n16=m, q) holds k=q*8+j ----
    f16x8 A1[4];
#pragma unroll
    for (int mt = 0; mt < 4; ++mt)
#pragma unroll
        for (int j = 0; j < 8; ++j) A1[mt][j] = (_Float16)0.0f;
    if (q == 0) {   // only k=0..5 nonzero
#pragma unroll
        for (int mt = 0; mt < 4; ++mt)
#pragma unroll
            for (int j = 0; j < 6; ++j)
                A1[mt][j] = (_Float16)W1[j * 64 + mt * 16 + n16];
    }

    f16x8 A2w[2][2];   // [mt][kt] = W2^T, M=32, K=64
#pragma unroll
    for (int mt = 0; mt < 2; ++mt)
#pragma unroll
        for (int kt = 0; kt < 2; ++kt)
#pragma unroll
            for (int j = 0; j < 8; ++j)
                A2w[mt][kt][j] = (_Float16)W2[(kt*32 + q*8 + j)*32 + mt*16 + n16];

    f16x8 A3w;         // W3^T, M=16, K=32
#pragma unroll
    for (int j = 0; j < 8; ++j)
        A3w[j] = (_Float16)W3[(q*8 + j)*16 + n16];

    // per-lane bias float4s: C rows are features m = mt*16 + q*4 + r
    f32x4 b1v[4], b2v[2], b3v;
#pragma unroll
    for (int mt = 0; mt < 4; ++mt) b1v[mt] = *(const f32x4*)(b1 + mt*16 + q*4);
#pragma unroll
    for (int mt = 0; mt < 2; ++mt) b2v[mt] = *(const f32x4*)(b2 + mt*16 + q*4);
    b3v = *(const f32x4*)(b3 + q*4);

    // ---- layer 1: h1^T = W1^T x^T  (M=64 feats, N=64 batch, K=32 pad) ----
    f16x8 BX[4];
    {
        const int xo   = (q == 0) ? (8176 + n16 * 16) : 9200;
        const int step = (q == 0) ? 256 : 0;
#pragma unroll
        for (int nt = 0; nt < 4; ++nt)
            BX[nt] = *(const f16x8*)(smem + xo + nt * step);
    }
#pragma unroll
    for (int mt = 0; mt < 4; ++mt) {
#pragma unroll
        for (int nt = 0; nt < 4; ++nt) {
            f32x4 C = b1v[mt];   // bias in C-in
            C = __builtin_amdgcn_mfma_f32_16x16x32_f16(A1[mt], BX[nt], C, 0, 0, 0);
            f16x4 hv;
#pragma unroll
            for (int r = 0; r < 4; ++r) hv[r] = (_Float16)fmaxf(C[r], 0.0f);
            // h1[b = nt*16+n16][m = mt*16+q*4 .. +3]
            *(f16x4*)(smem + (nt*16 + n16) * 144 + mt*32 + q*8) = hv;
        }
    }

    // ---- layer 2: h2^T = W2^T h1^T  (M=32, N=64, K=64) ----
    f16x8 H1f[4][2];   // pre-read ALL h1 B-fragments before h2 aliases it
#pragma unroll
    for (int nt = 0; nt < 4; ++nt)
#pragma unroll
        for (int kt = 0; kt < 2; ++kt)
            H1f[nt][kt] = *(const f16x8*)(smem + (nt*16 + n16) * 144 + kt*64 + q*16);
#pragma unroll
    for (int mt = 0; mt < 2; ++mt) {
#pragma unroll
        for (int nt = 0; nt < 4; ++nt) {
            f32x4 C = b2v[mt];
            C = __builtin_amdgcn_mfma_f32_16x16x32_f16(A2w[mt][0], H1f[nt][0], C, 0, 0, 0);
            C = __builtin_amdgcn_mfma_f32_16x16x32_f16(A2w[mt][1], H1f[nt][1], C, 0, 0, 0);
            f16x4 hv;
#pragma unroll
            for (int r = 0; r < 4; ++r) hv[r] = (_Float16)fmaxf(C[r], 0.0f);
            // h2[b][m = mt*16+q*4 .. +3]
            *(f16x4*)(smem + (nt*16 + n16) * 80 + mt*32 + q*8) = hv;
        }
    }

    // ---- layer 3: h3^T = W3^T h2^T  (M=16, N=64, K=32) ----
    f16x8 H2f[4];
#pragma unroll
    for (int nt = 0; nt < 4; ++nt)
        H2f[nt] = *(const f16x8*)(smem + (nt*16 + n16) * 80 + q*16);
#pragma unroll
    for (int nt = 0; nt < 4; ++nt) {
        f32x4 C = b3v;
        C = __builtin_amdgcn_mfma_f32_16x16x32_f16(A3w, H2f[nt], C, 0, 0, 0);
        f32x4 o;
#pragma unroll
        for (int r = 0; r < 4; ++r) o[r] = fmaxf(C[r], 0.0f);
        // h3[b][q*4 .. +3] as f32
        *(f32x4*)(smem + (nt*16 + n16) * 80 + q*16) = o;
    }

    // ---- each lane reads its own h3 row ----
    float h3[16];
    {
        const char* rp = smem + lane * 80;
#pragma unroll
        for (int i = 0; i < 4; ++i)
            *(f32x4*)&h3[4*i] = *(const f32x4*)(rp + i * 16);
    }

    // ---- scalar layer 4: 16 -> 9 (f32 for head precision) ----
    float p[9];
#pragma unroll
    for (int k = 0; k < 9; ++k) p[k] = fmaf(h3[0], W4[k], b4[k]);
#pragma unroll
    for (int j = 1; j < 16; ++j) {
        const float hj = h3[j];
        const float* w = W4 + j * 9;
#pragma unroll
        for (int k = 0; k < 9; ++k) p[k] = fmaf(hj, w[k], p[k]);
    }

    // ---- heads ----
    const float K00 = __expf(p[0]), K01 = __expf(p[1]);
    const float K10 = __expf(p[2]), K11 = __expf(p[3]);

    const float sh_m0 = kLOW + (kHIGH - kLOW) * fast_sigmoid(p[4]);
    const float sh_m1 = kLOW + (kHIGH - kLOW) * fast_sigmoid(p[5]);
    const float sh_f0 = kLOW + (kHIGH - kLOW) * fast_sigmoid(p[6]);
    const float sh_f1 = kLOW + (kHIGH - kLOW) * fast_sigmoid(p[7]);
    const float V = __expf(p[8]);

    const float M0 = x[0], M1 = x[1], M2 = x[2];
    const float F0 = x[3], F1 = x[4], F2 = x[5];

    const float r0 = M0 * sh_m0, r1 = M1 * sh_m1, r2 = M2;
    const float c0 = F0 * sh_f0, c1 = F1 * sh_f1, c2 = F2;
    const float mum0_0 = M0 * (1.0f - sh_m0), mum0_1 = M1 * (1.0f - sh_m1);
    const float mu0f_0 = F0 * (1.0f - sh_f0), mu0f_1 = F1 * (1.0f - sh_f1);

    // ---- Sinkhorn in u/v form, gauge-fixed v2==1 for iters 1..9 ----
    // K = [[K00,K01,1],[K10,K11,1],[1,1,1]]; A = diag(u) K diag(v).
    // Rescaling v between iterations leaves the next iteration's A
    // invariant (u compensates), so normalize v by t2/c2 each iter:
    // v0 = (c0/c2)*t2/t0, v1 = (c1/c2)*t2/t1, v2 = 1 -> one rcp saved.
    // Iter 10 uses the TRUE column step (c/t) so A == reference exactly.
    const float rc2 = fast_rcp(c2);
    const float g0 = c0 * rc2, g1 = c1 * rc2;
    float v0 = 1.0f, v1 = 1.0f;
    float u0, u1, u2;
#pragma unroll
    for (int it = 0; it < 9; ++it) {
        const float s0 = fmaf(K00, v0, fmaf(K01, v1, 1.0f));
        const float s1 = fmaf(K10, v0, fmaf(K11, v1, 1.0f));
        const float s2 = v0 + v1 + 1.0f;
        u0 = r0 * fast_rcp(s0);
        u1 = r1 * fast_rcp(s1);
        u2 = r2 * fast_rcp(s2);
        const float t0 = fmaf(K00, u0, fmaf(K10, u1, u2));
        const float t1 = fmaf(K01, u0, fmaf(K11, u1, u2));
        const float t2 = u0 + u1 + u2;
        v0 = g0 * (t2 * fast_rcp(t0));
        v1 = g1 * (t2 * fast_rcp(t1));
    }
    // iteration 10: row step + standard column step
    float vf0, vf1, vf2;
    {
        const float s0 = fmaf(K00, v0, fmaf(K01, v1, 1.0f));
        const float s1 = fmaf(K10, v0, fmaf(K11, v1, 1.0f));
        const float s2 = v0 + v1 + 1.0f;
        u0 = r0 * fast_rcp(s0);
        u1 = r1 * fast_rcp(s1);
        u2 = r2 * fast_rcp(s2);
        const float t0 = fmaf(K00, u0, fmaf(K10, u1, u2));
        const float t1 = fmaf(K01, u0, fmaf(K11, u1, u2));
        const float t2 = u0 + u1 + u2;
        vf0 = c0 * fast_rcp(t0);
        vf1 = c1 * fast_rcp(t1);
        vf2 = c2 * fast_rcp(t2);
    }
    const float A00 = u0 * K00 * vf0, A01 = u0 * K01 * vf1, A02 = u0 * vf2;
    const float A10 = u1 * K10 * vf0, A11 = u1 * K11 * vf1, A12 = u1 * vf2;
    const float A20 = u2 * vf0,       A21 = u2 * vf1,       A22 = u2 * vf2;

    // ---- store ----
    if (row < B) {
        float4* o = (float4*)(out_mus + (size_t)row * 16);
        o[0] = make_float4(A00, A01, A02, mum0_0);
        o[1] = make_float4(A10, A11, A12, mum0_1);
        o[2] = make_float4(A20, A21, A22, 0.0f);
        o[3] = make_float4(mu0f_0, mu0f_1, 0.0f, 0.0f);
        out_V[row] = V;
    }
}

extern "C" void kernel_launch(void* const* d_in, const int* in_sizes, int n_in,
                              void* d_out, int out_size, void* d_ws, size_t ws_size,
                              hipStream_t stream) {
    const float* margins = (const float*)d_in[0];
    const float* W1 = (const float*)d_in[1];
    const float* b1 = (const float*)d_in[2];
    const float* W2 = (const float*)d_in[3];
    const float* b2 = (const float*)d_in[4];
    const float* W3 = (const float*)d_in[5];
    const float* b3 = (const float*)d_in[6];
    const float* W4 = (const float*)d_in[7];
    const float* b4 = (const float*)d_in[8];

    const int B = in_sizes[0] / 6;
    float* out_mus = (float*)d_out;
    float* out_V   = out_mus + (size_t)B * 16;

    dim3 block(256);
    dim3 grid((B + 255) / 256);
    hipLaunchKernelGGL(sinkhorn_mlp_mfma, grid, block, 0, stream,
                       margins, W1, b1, W2, b2, W3, b3, W4, b4,
                       out_mus, out_V, B);
}

// Round 2
// 224.467 us; speedup vs baseline: 1.0200x; 1.0119x over previous
//
#include <hip/hip_runtime.h>

typedef _Float16 f16x8 __attribute__((ext_vector_type(8)));
typedef _Float16 f16x4 __attribute__((ext_vector_type(4)));
typedef float    f32x4 __attribute__((ext_vector_type(4)));

static constexpr float kLOW  = 0.02f;
static constexpr float kHIGH = 0.98f;

__device__ __forceinline__ float fast_rcp(float v) {
    return __builtin_amdgcn_rcpf(v);  // v_rcp_f32, ~1e-7 rel err
}
__device__ __forceinline__ float fast_sigmoid(float v) {
    // rcp instead of true divide: saves the ~10-inst div_fixup sequence
    return fast_rcp(1.0f + __expf(-v));
}

// ---------------- workspace layout (bytes) ----------------
// All fragments stored per-lane (64 entries of 16 B), so the main kernel
// loads each with ONE coalesced global_load_dwordx4.
enum : int {
    WS_A1 = 0,        // [4 mt][64 lane] f16x8   W1^T frags (K=32 pad, q>0 zero)
    WS_A2 = 4096,     // [2 mt][2 kt][64] f16x8  W2^T frags
    WS_A3 = 8192,     // [64] f16x8              W3^T frag
    WS_A4 = 9216,     // [64] f16x8              W4^T frag (M=16 pad, K=32 pad)
    WS_B1 = 10240,    // [4 mt][64] f32x4        b1 per-lane C-in rows
    WS_B2 = 14336,    // [2 mt][64] f32x4
    WS_B3 = 16384,    // [64] f32x4
    WS_B4 = 17408,    // [64] f32x4 (rows >=9 zeroed)
    WS_TOTAL = 18432
};

// One tiny dispatch per launch: packs wave-invariant W/bias data into the
// exact per-lane fragment layout. Replaces ~150 VALU insts (scattered loads
// + cvt + pack) in EVERY main-kernel wave with 18 coalesced b128 loads.
__global__ __launch_bounds__(256) void prep_frags(
    const float* __restrict__ W1, const float* __restrict__ b1,
    const float* __restrict__ W2, const float* __restrict__ b2,
    const float* __restrict__ W3, const float* __restrict__ b3,
    const float* __restrict__ W4, const float* __restrict__ b4,
    char* __restrict__ ws)
{
    const int lane = threadIdx.x & 63;
    const int wid  = threadIdx.x >> 6;
    const int n16  = lane & 15;
    const int q    = lane >> 4;

    if (wid == 0) {
        // A1: lane n16 = out-feature (mod 16), k = q*8+j; only k<6 nonzero
#pragma unroll
        for (int mt = 0; mt < 4; ++mt) {
            f16x8 a;
#pragma unroll
            for (int j = 0; j < 8; ++j) a[j] = (_Float16)0.0f;
            if (q == 0) {
#pragma unroll
                for (int j = 0; j < 6; ++j)
                    a[j] = (_Float16)W1[j * 64 + mt * 16 + n16];
            }
            ((f16x8*)(ws + WS_A1))[mt * 64 + lane] = a;
        }
#pragma unroll
        for (int mt = 0; mt < 4; ++mt)
            ((f32x4*)(ws + WS_B1))[mt * 64 + lane] = *(const f32x4*)(b1 + mt * 16 + q * 4);
    } else if (wid == 1) {
        // A2: W2^T, M=32, K=64
#pragma unroll
        for (int mt = 0; mt < 2; ++mt)
#pragma unroll
            for (int kt = 0; kt < 2; ++kt) {
                f16x8 a;
#pragma unroll
                for (int j = 0; j < 8; ++j)
                    a[j] = (_Float16)W2[(kt * 32 + q * 8 + j) * 32 + mt * 16 + n16];
                ((f16x8*)(ws + WS_A2))[(mt * 2 + kt) * 64 + lane] = a;
            }
    } else if (wid == 2) {
        // A3: W3^T, M=16, K=32
        f16x8 a3;
#pragma unroll
        for (int j = 0; j < 8; ++j)
            a3[j] = (_Float16)W3[(q * 8 + j) * 16 + n16];
        ((f16x8*)(ws + WS_A3))[lane] = a3;
        // A4: W4^T, M=16 (9 used), K=32 (16 used)
        f16x8 a4;
#pragma unroll
        for (int j = 0; j < 8; ++j) {
            const int k = q * 8 + j;
            a4[j] = (k < 16 && n16 < 9) ? (_Float16)W4[k * 9 + n16] : (_Float16)0.0f;
        }
        ((f16x8*)(ws + WS_A4))[lane] = a4;
    } else {
#pragma unroll
        for (int mt = 0; mt < 2; ++mt)
            ((f32x4*)(ws + WS_B2))[mt * 64 + lane] = *(const f32x4*)(b2 + mt * 16 + q * 4);
        ((f32x4*)(ws + WS_B3))[lane] = *(const f32x4*)(b3 + q * 4);
        f32x4 bb;
#pragma unroll
        for (int r = 0; r < 4; ++r) {
            const int m = q * 4 + r;
            bb[r] = (m < 9) ? b4[m] : 0.0f;
        }
        ((f32x4*)(ws + WS_B4))[lane] = bb;
    }
}

// Per-wave LDS slice 9216 B, regions (time-multiplexed, all hazards are
// read-before-overwrite within the same wave; compiler orders via lgkmcnt):
//   x^T f16 rows @ 8176..9200, zero 16B tile @ 9200..9216 (survives whole kernel)
//   h1 f16 [b][64] stride 144 @ 0..9200            (written after x frags read)
//   h2 f16 [b][32] stride  80 @ 0..5104            (written after h1 frags read)
//   h3 f16 [b][16] stride  32 @ 0..2048            (written after h2 frags read)
//   pbuf f32 [b][12+4pad] stride 80 @ 2560..7664   (written after h3 frags read)
__global__ __launch_bounds__(256, 4) void sinkhorn_mlp_mfma(
    const float* __restrict__ margins, const char* __restrict__ ws,
    float* __restrict__ out_mus, float* __restrict__ out_V, int B)
{
    __shared__ __align__(16) char smem_all[4 * 9216];
    const int lane = threadIdx.x & 63;
    const int wid  = threadIdx.x >> 6;
    char* smem = smem_all + wid * 9216;

    const int n16 = lane & 15;   // MFMA tile row/col index
    const int q   = lane >> 4;   // quad 0..3

    const int row  = blockIdx.x * 256 + wid * 64 + lane;
    const int rowC = row < B ? row : (B - 1);

    // ---- load input row (f32 kept for sinkhorn margins) ----
    float x[6];
    {
        const float2* mp = (const float2*)(margins + (size_t)rowC * 6);
        const float2 a = mp[0], b = mp[1], c = mp[2];
        x[0] = a.x; x[1] = a.y; x[2] = b.x; x[3] = b.y; x[4] = c.x; x[5] = c.y;
    }

    // ---- stage x^T rows as f16 (k=0..5 data, 6..7 zero) + zero tile ----
    {
        f16x8 xr;
#pragma unroll
        for (int j = 0; j < 8; ++j) xr[j] = (_Float16)0.0f;
#pragma unroll
        for (int i = 0; i < 6; ++i) xr[i] = (_Float16)x[i];
        *(f16x8*)(smem + 8176 + lane * 16) = xr;
        if (lane == 0) {
            f16x8 z;
#pragma unroll
            for (int j = 0; j < 8; ++j) z[j] = (_Float16)0.0f;
            *(f16x8*)(smem + 9200) = z;   // shared zero tile (L1 + L4 K-pad)
        }
    }

    // ---- fragments: coalesced b128 loads from prepacked ws ----
    f16x8 A1[4], A2w[2][2], A3w, A4w;
#pragma unroll
    for (int mt = 0; mt < 4; ++mt) A1[mt] = ((const f16x8*)(ws + WS_A1))[mt * 64 + lane];
#pragma unroll
    for (int mt = 0; mt < 2; ++mt)
#pragma unroll
        for (int kt = 0; kt < 2; ++kt)
            A2w[mt][kt] = ((const f16x8*)(ws + WS_A2))[(mt * 2 + kt) * 64 + lane];
    A3w = ((const f16x8*)(ws + WS_A3))[lane];
    A4w = ((const f16x8*)(ws + WS_A4))[lane];

    f32x4 b1v[4], b2v[2], b3v, b4v;
#pragma unroll
    for (int mt = 0; mt < 4; ++mt) b1v[mt] = ((const f32x4*)(ws + WS_B1))[mt * 64 + lane];
#pragma unroll
    for (int mt = 0; mt < 2; ++mt) b2v[mt] = ((const f32x4*)(ws + WS_B2))[mt * 64 + lane];
    b3v = ((const f32x4*)(ws + WS_B3))[lane];
    b4v = ((const f32x4*)(ws + WS_B4))[lane];

    // ---- layer 1: h1^T = W1^T x^T  (M=64, N=64, K=32 pad) ----
    f16x8 BX[4];
    {
        const int xo   = (q == 0) ? (8176 + n16 * 16) : 9200;
        const int step = (q == 0) ? 256 : 0;
#pragma unroll
        for (int nt = 0; nt < 4; ++nt)
            BX[nt] = *(const f16x8*)(smem + xo + nt * step);
    }
#pragma unroll
    for (int mt = 0; mt < 4; ++mt) {
#pragma unroll
        for (int nt = 0; nt < 4; ++nt) {
            f32x4 C = b1v[mt];
            C = __builtin_amdgcn_mfma_f32_16x16x32_f16(A1[mt], BX[nt], C, 0, 0, 0);
            f16x4 hv;
#pragma unroll
            for (int r = 0; r < 4; ++r) hv[r] = (_Float16)fmaxf(C[r], 0.0f);
            *(f16x4*)(smem + (nt*16 + n16) * 144 + mt*32 + q*8) = hv;
        }
    }

    // ---- layer 2: h2^T = W2^T h1^T  (M=32, N=64, K=64) ----
    f16x8 H1f[4][2];
#pragma unroll
    for (int nt = 0; nt < 4; ++nt)
#pragma unroll
        for (int kt = 0; kt < 2; ++kt)
            H1f[nt][kt] = *(const f16x8*)(smem + (nt*16 + n16) * 144 + kt*64 + q*16);
#pragma unroll
    for (int mt = 0; mt < 2; ++mt) {
#pragma unroll
        for (int nt = 0; nt < 4; ++nt) {
            f32x4 C = b2v[mt];
            C = __builtin_amdgcn_mfma_f32_16x16x32_f16(A2w[mt][0], H1f[nt][0], C, 0, 0, 0);
            C = __builtin_amdgcn_mfma_f32_16x16x32_f16(A2w[mt][1], H1f[nt][1], C, 0, 0, 0);
            f16x4 hv;
#pragma unroll
            for (int r = 0; r < 4; ++r) hv[r] = (_Float16)fmaxf(C[r], 0.0f);
            *(f16x4*)(smem + (nt*16 + n16) * 80 + mt*32 + q*8) = hv;
        }
    }

    // ---- layer 3: h3^T = W3^T h2^T  (M=16, N=64, K=32) -> h3 f16 [b][16] ----
    f16x8 H2f[4];
#pragma unroll
    for (int nt = 0; nt < 4; ++nt)
        H2f[nt] = *(const f16x8*)(smem + (nt*16 + n16) * 80 + q*16);
#pragma unroll
    for (int nt = 0; nt < 4; ++nt) {
        f32x4 C = b3v;
        C = __builtin_amdgcn_mfma_f32_16x16x32_f16(A3w, H2f[nt], C, 0, 0, 0);
        f16x4 hv;
#pragma unroll
        for (int r = 0; r < 4; ++r) hv[r] = (_Float16)fmaxf(C[r], 0.0f);
        // h3[b = nt*16+n16][feat q*4 .. +3] as f16, row stride 32 B
        *(f16x4*)(smem + (nt*16 + n16) * 32 + q*8) = hv;
    }

    // ---- layer 4 on MFMA: p^T = W4^T h3^T  (M=16 pad(9), N=64, K=32 pad(16)) ----
    f16x8 B4[4];
#pragma unroll
    for (int nt = 0; nt < 4; ++nt) {
        const int off = (q < 2) ? ((nt*16 + n16) * 32 + q * 16) : 9200;  // K 16..31 -> zero
        B4[nt] = *(const f16x8*)(smem + off);
    }
#pragma unroll
    for (int nt = 0; nt < 4; ++nt) {
        f32x4 C = b4v;
        C = __builtin_amdgcn_mfma_f32_16x16x32_f16(A4w, B4[nt], C, 0, 0, 0);
        // p[b = nt*16+n16][q*4 .. +3] f32; rows 9..15 are pad (q=3 + part of q=2)
        *(f32x4*)(smem + 2560 + (nt*16 + n16) * 80 + q * 16) = C;
    }

    // ---- each lane reads its own p row ----
    float p[9];
    {
        const char* pr = smem + 2560 + lane * 80;
        *(f32x4*)&p[0] = *(const f32x4*)(pr);
        *(f32x4*)&p[4] = *(const f32x4*)(pr + 16);
        p[8] = *(const float*)(pr + 32);
    }

    // ---- heads ----
    const float K00 = __expf(p[0]), K01 = __expf(p[1]);
    const float K10 = __expf(p[2]), K11 = __expf(p[3]);

    const float sh_m0 = kLOW + (kHIGH - kLOW) * fast_sigmoid(p[4]);
    const float sh_m1 = kLOW + (kHIGH - kLOW) * fast_sigmoid(p[5]);
    const float sh_f0 = kLOW + (kHIGH - kLOW) * fast_sigmoid(p[6]);
    const float sh_f1 = kLOW + (kHIGH - kLOW) * fast_sigmoid(p[7]);
    const float V = __expf(p[8]);

    const float M0 = x[0], M1 = x[1], M2 = x[2];
    const float F0 = x[3], F1 = x[4], F2 = x[5];

    const float r0 = M0 * sh_m0, r1 = M1 * sh_m1, r2 = M2;
    const float c0 = F0 * sh_f0, c1 = F1 * sh_f1, c2 = F2;
    const float mum0_0 = M0 * (1.0f - sh_m0), mum0_1 = M1 * (1.0f - sh_m1);
    const float mu0f_0 = F0 * (1.0f - sh_f0), mu0f_1 = F1 * (1.0f - sh_f1);

    // ---- Sinkhorn in u/v form, gauge-fixed v2==1 for iters 1..9 ----
    // (v-rescaling between iterations is absorbed by u; iter 10 uses the
    // true column step so the final A matches the reference exactly.)
    const float rc2 = fast_rcp(c2);
    const float g0 = c0 * rc2, g1 = c1 * rc2;
    float v0 = 1.0f, v1 = 1.0f;
    float u0, u1, u2;
#pragma unroll
    for (int it = 0; it < 9; ++it) {
        const float s0 = fmaf(K00, v0, fmaf(K01, v1, 1.0f));
        const float s1 = fmaf(K10, v0, fmaf(K11, v1, 1.0f));
        const float s2 = v0 + v1 + 1.0f;
        u0 = r0 * fast_rcp(s0);
        u1 = r1 * fast_rcp(s1);
        u2 = r2 * fast_rcp(s2);
        const float t0 = fmaf(K00, u0, fmaf(K10, u1, u2));
        const float t1 = fmaf(K01, u0, fmaf(K11, u1, u2));
        const float t2 = u0 + u1 + u2;
        v0 = g0 * (t2 * fast_rcp(t0));
        v1 = g1 * (t2 * fast_rcp(t1));
    }
    float vf0, vf1, vf2;
    {
        const float s0 = fmaf(K00, v0, fmaf(K01, v1, 1.0f));
        const float s1 = fmaf(K10, v0, fmaf(K11, v1, 1.0f));
        const float s2 = v0 + v1 + 1.0f;
        u0 = r0 * fast_rcp(s0);
        u1 = r1 * fast_rcp(s1);
        u2 = r2 * fast_rcp(s2);
        const float t0 = fmaf(K00, u0, fmaf(K10, u1, u2));
        const float t1 = fmaf(K01, u0, fmaf(K11, u1, u2));
        const float t2 = u0 + u1 + u2;
        vf0 = c0 * fast_rcp(t0);
        vf1 = c1 * fast_rcp(t1);
        vf2 = c2 * fast_rcp(t2);
    }
    const float A00 = u0 * K00 * vf0, A01 = u0 * K01 * vf1, A02 = u0 * vf2;
    const float A10 = u1 * K10 * vf0, A11 = u1 * K11 * vf1, A12 = u1 * vf2;
    const float A20 = u2 * vf0,       A21 = u2 * vf1,       A22 = u2 * vf2;

    // ---- store ----
    if (row < B) {
        float4* o = (float4*)(out_mus + (size_t)row * 16);
        o[0] = make_float4(A00, A01, A02, mum0_0);
        o[1] = make_float4(A10, A11, A12, mum0_1);
        o[2] = make_float4(A20, A21, A22, 0.0f);
        o[3] = make_float4(mu0f_0, mu0f_1, 0.0f, 0.0f);
        out_V[row] = V;
    }
}

extern "C" void kernel_launch(void* const* d_in, const int* in_sizes, int n_in,
                              void* d_out, int out_size, void* d_ws, size_t ws_size,
                              hipStream_t stream) {
    const float* margins = (const float*)d_in[0];
    const float* W1 = (const float*)d_in[1];
    const float* b1 = (const float*)d_in[2];
    const float* W2 = (const float*)d_in[3];
    const float* b2 = (const float*)d_in[4];
    const float* W3 = (const float*)d_in[5];
    const float* b3 = (const float*)d_in[6];
    const float* W4 = (const float*)d_in[7];
    const float* b4 = (const float*)d_in[8];

    const int B = in_sizes[0] / 6;
    float* out_mus = (float*)d_out;
    float* out_V   = out_mus + (size_t)B * 16;
    char*  ws      = (char*)d_ws;

    hipLaunchKernelGGL(prep_frags, dim3(1), dim3(256), 0, stream,
                       W1, b1, W2, b2, W3, b3, W4, b4, ws);

    dim3 block(256);
    dim3 grid((B + 255) / 256);
    hipLaunchKernelGGL(sinkhorn_mlp_mfma, grid, block, 0, stream,
                       margins, ws, out_mus, out_V, B);
}